// Round 6
// baseline (67.335 us; speedup 1.0000x reference)
//
#include <hip/hip_runtime.h>

// CCAMDec: out = x + scale * softmax(max_k(E)-E) @ y,  E = x·yᵀ over HW
// N=8, C=512, K=64, HW=4096. softmax(max-E) == softmax(-E) (shift invariance).
#define N_ 8
#define C_ 512
#define K_ 64
#define HW_ 4096
#define NCH 16     // chunks per block in k_energy
#define CHS 256    // s per chunk

typedef __attribute__((ext_vector_type(8))) short short8;   // 8 bf16 (4 VGPRs) MFMA A/B frag
typedef __attribute__((ext_vector_type(4))) float floatx4;  // MFMA C/D frag

__device__ __forceinline__ float bf2f(unsigned short b){
  union { unsigned u; float f; } v; v.u = ((unsigned)b) << 16;
  return v.f;
}

// 8 f32 -> 8 bf16 via hardware v_cvt_pk_bf16_f32 (RNE, 1 instr / 2 elems)
__device__ __forceinline__ short8 cvt8(const float* __restrict__ p){
  float4 u = *(const float4*)p;
  float4 w = *(const float4*)(p + 4);
  union { unsigned u32[4]; short8 s; } r;
  asm("v_cvt_pk_bf16_f32 %0, %1, %2" : "=v"(r.u32[0]) : "v"(u.x), "v"(u.y));
  asm("v_cvt_pk_bf16_f32 %0, %1, %2" : "=v"(r.u32[1]) : "v"(u.z), "v"(u.w));
  asm("v_cvt_pk_bf16_f32 %0, %1, %2" : "=v"(r.u32[2]) : "v"(w.x), "v"(w.y));
  asm("v_cvt_pk_bf16_f32 %0, %1, %2" : "=v"(r.u32[3]) : "v"(w.z), "v"(w.w));
  return r.s;
}

// K0: y (f32, [n][k][s]) -> ybf (bf16 row-major [n][k][s]) and ytr (bf16 [n][s][k])
__global__ __launch_bounds__(256) void k_prep(const float* __restrict__ y,
                                              unsigned short* __restrict__ ybf,
                                              unsigned short* __restrict__ ytr){
  __shared__ unsigned short tile[64][72];
  int n  = blockIdx.x >> 6;                 // 64 s-tiles per batch
  int s0 = (blockIdx.x & 63) << 6;
  int tid = threadIdx.x;
  int k  = tid >> 2;
  int sc = (tid & 3) << 4;
  const float* yp = y + ((size_t)n * K_ + k) * HW_ + s0 + sc;
  union { unsigned short u16[16]; short8 s8[2]; uint4 q[2]; } u;
  u.s8[0] = cvt8(yp);
  u.s8[1] = cvt8(yp + 8);
  unsigned short* rp = ybf + ((size_t)n * K_ + k) * HW_ + s0 + sc;
  *(uint4*)rp       = u.q[0];
  *(uint4*)(rp + 8) = u.q[1];
#pragma unroll
  for (int j = 0; j < 16; ++j) tile[sc + j][k] = u.u16[j];
  __syncthreads();
  int s  = tid >> 2;
  int kc = (tid & 3) << 4;
  unsigned short* tp = ytr + ((size_t)n * HW_ + s0 + s) * K_ + kc;
  *(uint4*)tp       = *(const uint4*)&tile[s][kc];
  *(uint4*)(tp + 8) = *(const uint4*)&tile[s][kc + 8];
}

// K1: fused energy + softmax.  Block = (n, 16c), 512 threads (8 waves),
// full s-range, 16 chunks of 256 s.  48 staging "slots" per chunk
// (16 A-rows of x  +  32 B-pair-rows of ybf), 6 per wave, each a single
// 16 B/lane (1 KB/wave) global load.  Register double-buffer: chunk ch+1's
// loads issue right after the first barrier and are consumed next iter —
// explicit MLP the compiler wasn't providing.  Wave w=(h,q): k-quadrant q,
// s-half h of each chunk; E[16c][64k] accumulated in regs over full s,
// reduced via LDS, softmax(-E) in-block, att -> bf16 global.
template<bool WRITE_XBF>
__global__ __launch_bounds__(512, 2) void k_energy(const float* __restrict__ x,
                                                   const unsigned short* __restrict__ ybf,
                                                   unsigned short* __restrict__ att,
                                                   unsigned short* __restrict__ xbf){
  __shared__ unsigned short As[16 * 256];   // 8 KB,  pitch 512 B, XOR-swizzled
  __shared__ unsigned short Bs[64 * 256];   // 32 KB, pitch 512 B, XOR-swizzled
  __shared__ float Els[2][16][64];          // 8 KB   E partials (per s-half)
  const int bid = blockIdx.x;               // 8n * 32ct = 256
  const int ct = bid & 31, n = bid >> 5;
  const int tid = threadIdx.x;
  const int w = tid >> 6, l = tid & 63;
  const int lo = l & 15, hi = l >> 4;
  const int q = w & 3, h = w >> 2;
  const int c0 = ct << 4;

  // slot setup: idx = w*6+j; idx<16 -> A-row idx; else B-pair idx-16
  const char* gp[6];        // global src (lane-resolved)
  unsigned short* xp[6];    // xbf dst (A slots)
  char* lp[6];              // LDS dst (swizzled, chunk-invariant)
  int stA[6];               // is A slot
  int gstride[6];           // bytes per chunk
#pragma unroll
  for (int j = 0; j < 6; ++j){
    int idx = w * 6 + j;
    if (idx < 16){
      int r = idx;
      gp[j] = (const char*)(x + ((size_t)n * C_ + c0 + r) * HW_ + 4 * l);
      xp[j] = xbf + ((size_t)n * C_ + c0 + r) * HW_ + 4 * l;
      lp[j] = (char*)As + r * 512 + ((8 * l) ^ ((r & 7) << 4));
      stA[j] = 1; gstride[j] = CHS * 4;
    } else {
      int kk = 2 * (idx - 16) + (l >> 5);
      gp[j] = (const char*)(ybf + ((size_t)n * K_ + kk) * HW_ + 8 * (l & 31));
      xp[j] = nullptr;
      lp[j] = (char*)Bs + kk * 512 + ((16 * (l & 31)) ^ ((kk & 7) << 4));
      stA[j] = 0; gstride[j] = CHS * 2;
    }
  }

  uint4 bufA[6], bufB[6];
  floatx4 acc = {0.f, 0.f, 0.f, 0.f};

#pragma unroll
  for (int j = 0; j < 6; ++j) bufA[j] = *(const uint4*)(gp[j]);

#define EN_BODY(CH, CUR, NXT)                                                  \
  {                                                                            \
    _Pragma("unroll")                                                          \
    for (int j = 0; j < 6; ++j){                                               \
      if (stA[j]){                                                             \
        float4 v = *(float4*)&CUR[j];                                          \
        unsigned d0, d1;                                                       \
        asm("v_cvt_pk_bf16_f32 %0, %1, %2" : "=v"(d0) : "v"(v.x), "v"(v.y));   \
        asm("v_cvt_pk_bf16_f32 %0, %1, %2" : "=v"(d1) : "v"(v.z), "v"(v.w));   \
        uint2 dd; dd.x = d0; dd.y = d1;                                        \
        if (WRITE_XBF) *(uint2*)(xp[j] + (size_t)(CH) * CHS) = dd;             \
        *(uint2*)(lp[j]) = dd;                                                 \
      } else {                                                                 \
        *(uint4*)(lp[j]) = CUR[j];                                             \
      }                                                                        \
    }                                                                          \
    __syncthreads();                                                           \
    if ((CH) + 1 < NCH){                                                       \
      _Pragma("unroll")                                                        \
      for (int j = 0; j < 6; ++j)                                              \
        NXT[j] = *(const uint4*)(gp[j] + (size_t)((CH) + 1) * gstride[j]);     \
    }                                                                          \
    _Pragma("unroll")                                                          \
    for (int sl = 0; sl < 4; ++sl){                                            \
      int ss = h * 4 + sl;                                                     \
      int off = (ss * 64 + hi * 16) ^ ((lo & 7) << 4);                         \
      short8 a = *(const short8*)((const char*)As + lo * 512 + off);           \
      short8 b = *(const short8*)((const char*)Bs + (q * 16 + lo) * 512 + off);\
      acc = __builtin_amdgcn_mfma_f32_16x16x32_bf16(a, b, acc, 0, 0, 0);       \
    }                                                                          \
    __syncthreads();                                                           \
  }

#pragma unroll
  for (int cp = 0; cp < NCH / 2; ++cp){
    EN_BODY(2 * cp,     bufA, bufB)
    EN_BODY(2 * cp + 1, bufB, bufA)
  }
#undef EN_BODY

  // dump E partials: D layout col=lo -> k=q*16+lo, row=hi*4+r -> c
#pragma unroll
  for (int r = 0; r < 4; ++r) Els[h][hi * 4 + r][q * 16 + lo] = acc[r];
  __syncthreads();

  // softmax(-E) per c-row: threads 0..255, 16 threads per row, 4 k each
  if (tid < 256){
    int c = tid >> 4, j = tid & 15;
    float e0 = Els[0][c][4 * j + 0] + Els[1][c][4 * j + 0];
    float e1 = Els[0][c][4 * j + 1] + Els[1][c][4 * j + 1];
    float e2 = Els[0][c][4 * j + 2] + Els[1][c][4 * j + 2];
    float e3 = Els[0][c][4 * j + 3] + Els[1][c][4 * j + 3];
    float m = fminf(fminf(e0, e1), fminf(e2, e3));
#pragma unroll
    for (int off = 8; off; off >>= 1) m = fminf(m, __shfl_xor(m, off, 16));
    float p0 = __expf(m - e0), p1 = __expf(m - e1);
    float p2 = __expf(m - e2), p3 = __expf(m - e3);
    float s = p0 + p1 + p2 + p3;
#pragma unroll
    for (int off = 8; off; off >>= 1) s += __shfl_xor(s, off, 16);
    float inv = 1.f / s;
    unsigned d0, d1;
    asm("v_cvt_pk_bf16_f32 %0, %1, %2" : "=v"(d0) : "v"(p0 * inv), "v"(p1 * inv));
    asm("v_cvt_pk_bf16_f32 %0, %1, %2" : "=v"(d1) : "v"(p2 * inv), "v"(p3 * inv));
    uint2 dd; dd.x = d0; dd.y = d1;
    *(uint2*)(att + ((size_t)n * C_ + c0 + c) * K_ + 4 * j) = dd;
  }
}

// K3: out = x + scale * att @ y.  4 waves/block; block tile 16c x 512s
// (128s per wave). Epilogue: per 32-s double-subtile, transpose acc through
// LDS so each lane owns (1 row, 8 consecutive s) -> 16B bf16 x-load (xbf) +
// 2x16B f32 out-store.
template<bool USE_XBF>
__global__ __launch_bounds__(256) void k_out(const float* __restrict__ x,
                                             const unsigned short* __restrict__ xbf,
                                             const unsigned short* __restrict__ att,
                                             const unsigned short* __restrict__ ytr,
                                             const float* __restrict__ scale,
                                             float* __restrict__ out){
  __shared__ float xt[4][16][36];  // per-wave 16x32 transpose buffer, stride 36
  int bid = blockIdx.x;            // 8n * 32ct * 8sb = 2048
  int sb = bid & 7;
  int ct = (bid >> 3) & 31;
  int n  = bid >> 8;
  int w  = threadIdx.x >> 6;
  int l  = threadIdx.x & 63, lo = l & 15, hi = l >> 4;
  int c0 = ct << 4;
  int s0 = (sb << 9) + (w << 7);   // 512 per block, 128 per wave
  float sc = scale[0];

  const unsigned short* ap = att + ((size_t)n * C_ + c0 + lo) * K_ + hi * 8;
  short8 a0 = *(const short8*)(ap);        // k = hi*8+j
  short8 a1 = *(const short8*)(ap + 32);   // k = 32 + hi*8+j

  const unsigned short* bp0 = ytr + ((size_t)n * HW_ + s0 + lo) * K_ + hi * 8;
  int row = l >> 2, c8 = (l & 3) << 3;     // epilogue: lane -> (row, 8 cols)
  size_t eoff = ((size_t)n * C_ + c0 + row) * HW_ + s0 + c8;
  const float*          xp = x   + eoff;
  const unsigned short* xq = xbf + eoff;
  float*                op = out + eoff;
  float (*T)[36] = xt[w];

#pragma unroll
  for (int p = 0; p < 4; ++p){
    const unsigned short* bp = bp0 + (size_t)(p * 32) * K_;
    short8 b0 = *(const short8*)(bp);
    short8 b1 = *(const short8*)(bp + 32);
    short8 b2 = *(const short8*)(bp + 16 * K_);
    short8 b3 = *(const short8*)(bp + 16 * K_ + 32);
    floatx4 acc0 = {0.f,0.f,0.f,0.f};
    floatx4 acc1 = {0.f,0.f,0.f,0.f};
    acc0 = __builtin_amdgcn_mfma_f32_16x16x32_bf16(a0, b0, acc0, 0, 0, 0);
    acc0 = __builtin_amdgcn_mfma_f32_16x16x32_bf16(a1, b1, acc0, 0, 0, 0);
    acc1 = __builtin_amdgcn_mfma_f32_16x16x32_bf16(a0, b2, acc1, 0, 0, 0);
    acc1 = __builtin_amdgcn_mfma_f32_16x16x32_bf16(a1, b3, acc1, 0, 0, 0);
    // acc layout: row = hi*4+r, col = lo (acc0: s+0..15, acc1: s+16..31)
#pragma unroll
    for (int r = 0; r < 4; ++r){
      T[hi * 4 + r][lo]      = acc0[r];
      T[hi * 4 + r][16 + lo] = acc1[r];
    }
    float4 v0 = *(const float4*)&T[row][c8];       // in-wave DS ordering
    float4 v1 = *(const float4*)&T[row][c8 + 4];
    float xf[8];
    if (USE_XBF){
      short8 xv = *(const short8*)(xq + p * 32);
#pragma unroll
      for (int j = 0; j < 8; ++j) xf[j] = bf2f((unsigned short)xv[j]);
    } else {
      float4 u0 = *(const float4*)(xp + p * 32);
      float4 u1 = *(const float4*)(xp + p * 32 + 4);
      xf[0]=u0.x; xf[1]=u0.y; xf[2]=u0.z; xf[3]=u0.w;
      xf[4]=u1.x; xf[5]=u1.y; xf[6]=u1.z; xf[7]=u1.w;
    }
    float4 o0, o1;
    o0.x = xf[0] + sc * v0.x; o0.y = xf[1] + sc * v0.y;
    o0.z = xf[2] + sc * v0.z; o0.w = xf[3] + sc * v0.w;
    o1.x = xf[4] + sc * v1.x; o1.y = xf[5] + sc * v1.y;
    o1.z = xf[6] + sc * v1.z; o1.w = xf[7] + sc * v1.w;
    *(float4*)(op + p * 32)     = o0;
    *(float4*)(op + p * 32 + 4) = o1;
  }
}

extern "C" void kernel_launch(void* const* d_in, const int* in_sizes, int n_in,
                              void* d_out, int out_size, void* d_ws, size_t ws_size,
                              hipStream_t stream){
  const float* x     = (const float*)d_in[0];
  const float* y     = (const float*)d_in[1];
  const float* scale = (const float*)d_in[2];
  float* out = (float*)d_out;

  // ws layout:
  //   att : N*C*K bf16  = 512 KiB  @ 0   (1 MiB reserved)
  //   ybf : N*K*HW bf16 = 4 MiB    @ 1 MiB
  //   ytr : N*HW*K bf16 = 4 MiB    @ 5 MiB
  //   xbf : N*C*HW bf16 = 32 MiB   @ 9 MiB (optional)
  char* ws = (char*)d_ws;
  unsigned short* att = (unsigned short*)(ws);
  unsigned short* ybf = (unsigned short*)(ws + (1u<<20));
  unsigned short* ytr = (unsigned short*)(ws + (5u<<20));
  unsigned short* xbf = (unsigned short*)(ws + (9u<<20));
  bool use_xbf = ws_size >= (41u<<20);

  k_prep <<<N_ * (HW_/64), 256, 0, stream>>>(y, ybf, ytr);
  if (use_xbf){
    k_energy<true>  <<<N_ * 32, 512, 0, stream>>>(x, ybf, att, xbf);
    k_out<true>     <<<N_ * 32 * 8, 256, 0, stream>>>(x, xbf, att, ytr, scale, out);
  } else {
    k_energy<false> <<<N_ * 32, 512, 0, stream>>>(x, ybf, att, xbf);
    k_out<false>    <<<N_ * 32 * 8, 256, 0, stream>>>(x, xbf, att, ytr, scale, out);
  }
}

// Round 7
// 58.081 us; speedup vs baseline: 1.1593x; 1.1593x over previous
//
#include <hip/hip_runtime.h>

// CCAMDec: out = x + scale * softmax(max_k(E)-E) @ y,  E = x·yᵀ over HW
// N=8, C=512, K=64, HW=4096. softmax(max-E) == softmax(-E) (shift invariance).
#define N_ 8
#define C_ 512
#define K_ 64
#define HW_ 4096
#define SPLITS 4
#define SRANGE (HW_ / SPLITS)   // 1024 s per k_energy block
#define SCHUNK 128              // s per staged chunk (8 chunks)

typedef __attribute__((ext_vector_type(8))) short short8;   // 8 bf16 (4 VGPRs) MFMA A/B frag
typedef __attribute__((ext_vector_type(4))) float floatx4;  // MFMA C/D frag

__device__ __forceinline__ float bf2f(unsigned short b){
  union { unsigned u; float f; } v; v.u = ((unsigned)b) << 16;
  return v.f;
}

// 8 f32 -> 8 bf16 via hardware v_cvt_pk_bf16_f32 (RNE, 1 instr / 2 elems)
__device__ __forceinline__ short8 cvt8(const float* __restrict__ p){
  float4 u = *(const float4*)p;
  float4 w = *(const float4*)(p + 4);
  union { unsigned u32[4]; short8 s; } r;
  asm("v_cvt_pk_bf16_f32 %0, %1, %2" : "=v"(r.u32[0]) : "v"(u.x), "v"(u.y));
  asm("v_cvt_pk_bf16_f32 %0, %1, %2" : "=v"(r.u32[1]) : "v"(u.z), "v"(u.w));
  asm("v_cvt_pk_bf16_f32 %0, %1, %2" : "=v"(r.u32[2]) : "v"(w.x), "v"(w.y));
  asm("v_cvt_pk_bf16_f32 %0, %1, %2" : "=v"(r.u32[3]) : "v"(w.z), "v"(w.w));
  return r.s;
}

// async global -> LDS, 16 B/lane (1 KB/wave), zero VGPR cost
__device__ __forceinline__ void gload16(const void* g, void* l){
  __builtin_amdgcn_global_load_lds(
      (const __attribute__((address_space(1))) void*)g,
      (__attribute__((address_space(3))) void*)l, 16, 0, 0);
}

// K0: y (f32, [n][k][s]) -> ybf (bf16 row-major [n][k][s]) and ytr (bf16 [n][s][k])
__global__ __launch_bounds__(256) void k_prep(const float* __restrict__ y,
                                              unsigned short* __restrict__ ybf,
                                              unsigned short* __restrict__ ytr){
  __shared__ unsigned short tile[64][72];
  int n  = blockIdx.x >> 6;                 // 64 s-tiles per batch
  int s0 = (blockIdx.x & 63) << 6;
  int tid = threadIdx.x;
  int k  = tid >> 2;
  int sc = (tid & 3) << 4;
  const float* yp = y + ((size_t)n * K_ + k) * HW_ + s0 + sc;
  union { unsigned short u16[16]; short8 s8[2]; uint4 q[2]; } u;
  u.s8[0] = cvt8(yp);
  u.s8[1] = cvt8(yp + 8);
  unsigned short* rp = ybf + ((size_t)n * K_ + k) * HW_ + s0 + sc;
  *(uint4*)rp       = u.q[0];
  *(uint4*)(rp + 8) = u.q[1];
#pragma unroll
  for (int j = 0; j < 16; ++j) tile[sc + j][k] = u.u16[j];
  __syncthreads();
  int s  = tid >> 2;
  int kc = (tid & 3) << 4;
  unsigned short* tp = ytr + ((size_t)n * HW_ + s0 + s) * K_ + kc;
  *(uint4*)tp       = *(const uint4*)&tile[s][kc];
  *(uint4*)(tp + 8) = *(const uint4*)&tile[s][kc + 8];
}

// K1: partial energies, m97-shape loop.  Block = (n, 16c, 1024s), 4 waves.
// 8 chunks of 128 s; staging via global_load_lds width=16 ONLY (no VGPR
// round-trip): per chunk per wave 2 A-pair + 4 B-quad instrs, each 1 KB.
// Source-side XOR pre-swizzle ^((row&7)<<4), same XOR on ds_read (rule #21)
// -> <=2-way bank conflicts.  Wave w owns k-quadrant [16w,16w+16).
__global__ __launch_bounds__(256) void k_energy(const float* __restrict__ x,
                                                const unsigned short* __restrict__ ybf,
                                                float* __restrict__ partial){
  __shared__ char As[16 * 512];    // 8 KB:  16 c-rows x 128 f32 (512 B pitch)
  __shared__ char Bs[64 * 256];    // 16 KB: 64 k-rows x 128 bf16 (256 B pitch)
  const int bid = blockIdx.x;      // 8n * 32ct * 4sp = 1024
  const int sp = bid & 3;
  const int ct = (bid >> 2) & 31;
  const int n  = bid >> 7;
  const int tid = threadIdx.x;
  const int w = tid >> 6, l = tid & 63;
  const int lo = l & 15, hi = l >> 4;
  const int c0 = ct << 4;
  const int sb = sp * SRANGE;

  // chunk-invariant per-lane source offsets (bytes)
  const int ar  = ((w << 1) + 0) * 2 + (l >> 5);     // A row for pair j=0
  const int ar1 = ((w << 1) + 1) * 2 + (l >> 5);     // A row for pair j=1
  const char* asrc0 = (const char*)(x + ((size_t)n * C_ + c0 + ar ) * HW_ + sb)
                      + ((16 * (l & 31)) ^ ((ar  & 7) << 4));
  const char* asrc1 = (const char*)(x + ((size_t)n * C_ + c0 + ar1) * HW_ + sb)
                      + ((16 * (l & 31)) ^ ((ar1 & 7) << 4));
  const char* bsrc[4];
#pragma unroll
  for (int j = 0; j < 4; ++j){
    int qj = (w << 2) + j;
    int kk = (qj << 2) + (l >> 4);
    bsrc[j] = (const char*)(ybf + ((size_t)n * K_ + kk) * HW_ + sb)
              + ((16 * (l & 15)) ^ ((kk & 7) << 4));
  }

  floatx4 acc = {0.f, 0.f, 0.f, 0.f};
  const int kk_r = (w << 4) + lo;                    // compute-side B row
  const int bswz = (kk_r & 7) << 4;
  const int aswz = (lo & 7) << 4;

  for (int ch = 0; ch < SPLITS * 0 + 8; ++ch){
    // ---- stage chunk (6 x 1KB global_load_lds per wave, zero VGPR) ----
    gload16(asrc0 + (size_t)ch * (SCHUNK * 4), As + ((w << 1) + 0) * 1024);
    gload16(asrc1 + (size_t)ch * (SCHUNK * 4), As + ((w << 1) + 1) * 1024);
#pragma unroll
    for (int j = 0; j < 4; ++j)
      gload16(bsrc[j] + (size_t)ch * (SCHUNK * 2), Bs + ((w << 2) + j) * 1024);
    __syncthreads();                                  // drains vmcnt
    // ---- compute: 4 s-steps of 32 ----
#pragma unroll
    for (int ss = 0; ss < 4; ++ss){
      int aoff = ss * 128 + hi * 32;
      const char* ab = As + lo * 512;
      float4 a0f = *(const float4*)(ab + ((aoff     ) ^ aswz));
      float4 a1f = *(const float4*)(ab + ((aoff + 16) ^ aswz));
      union { unsigned u32[4]; short8 s; } af;
      asm("v_cvt_pk_bf16_f32 %0, %1, %2" : "=v"(af.u32[0]) : "v"(a0f.x), "v"(a0f.y));
      asm("v_cvt_pk_bf16_f32 %0, %1, %2" : "=v"(af.u32[1]) : "v"(a0f.z), "v"(a0f.w));
      asm("v_cvt_pk_bf16_f32 %0, %1, %2" : "=v"(af.u32[2]) : "v"(a1f.x), "v"(a1f.y));
      asm("v_cvt_pk_bf16_f32 %0, %1, %2" : "=v"(af.u32[3]) : "v"(a1f.z), "v"(a1f.w));
      short8 b = *(const short8*)(Bs + kk_r * 256 + ((ss * 64 + hi * 16) ^ bswz));
      acc = __builtin_amdgcn_mfma_f32_16x16x32_bf16(af.s, b, acc, 0, 0, 0);
    }
    __syncthreads();
  }

  // D layout: col = lo -> k = 16w+lo, row = hi*4+r -> c  [m89-verified]
  float* pp = partial + (((size_t)sp * N_ + n) * C_ + c0) * K_;
#pragma unroll
  for (int r = 0; r < 4; ++r)
    pp[(size_t)(hi * 4 + r) * K_ + kk_r] = acc[r];
}

// K2: reduce splits + softmax(-E) over k (wave-wide, K=64=wavefront), att -> bf16
__global__ __launch_bounds__(256) void k_softmax(const float* __restrict__ partial,
                                                 unsigned short* __restrict__ att){
  int wid = blockIdx.x * 4 + (threadIdx.x >> 6);  // (n,c) row id, 0..4095
  int l = threadIdx.x & 63;
  size_t base = (size_t)wid * K_ + l;
  float e = 0.f;
#pragma unroll
  for (int sp = 0; sp < SPLITS; ++sp) e += partial[(size_t)sp * (N_*C_*K_) + base];
  // softmax(-e): stabilize with min(e)
  float m = e;
#pragma unroll
  for (int off = 32; off > 0; off >>= 1) m = fminf(m, __shfl_xor(m, off));
  float p = __expf(m - e);
  float sum = p;
#pragma unroll
  for (int off = 32; off > 0; off >>= 1) sum += __shfl_xor(sum, off);
  union { unsigned u; float f; } v; v.f = p / sum;
  unsigned r = v.u + 0x7FFFu + ((v.u >> 16) & 1u);
  att[base] = (unsigned short)(r >> 16);
}

// K3: out = x + scale * att @ y.  4 waves/block; block tile 16c x 512s
// (128s per wave). Epilogue: per 32-s double-subtile, transpose acc through
// LDS so each lane owns (1 row, 8 consecutive s) -> float4 x-load (L3-hot) +
// 2x16B f32 out-store.
__global__ __launch_bounds__(256) void k_out(const float* __restrict__ x,
                                             const unsigned short* __restrict__ att,
                                             const unsigned short* __restrict__ ytr,
                                             const float* __restrict__ scale,
                                             float* __restrict__ out){
  __shared__ float xt[4][16][36];  // per-wave 16x32 transpose buffer, stride 36
  int bid = blockIdx.x;            // 8n * 32ct * 8sb = 2048
  int sb = bid & 7;
  int ct = (bid >> 3) & 31;
  int n  = bid >> 8;
  int w  = threadIdx.x >> 6;
  int l  = threadIdx.x & 63, lo = l & 15, hi = l >> 4;
  int c0 = ct << 4;
  int s0 = (sb << 9) + (w << 7);   // 512 per block, 128 per wave
  float sc = scale[0];

  const unsigned short* ap = att + ((size_t)n * C_ + c0 + lo) * K_ + hi * 8;
  short8 a0 = *(const short8*)(ap);        // k = hi*8+j
  short8 a1 = *(const short8*)(ap + 32);   // k = 32 + hi*8+j

  const unsigned short* bp0 = ytr + ((size_t)n * HW_ + s0 + lo) * K_ + hi * 8;
  int row = l >> 2, c8 = (l & 3) << 3;     // epilogue: lane -> (row, 8 cols)
  size_t eoff = ((size_t)n * C_ + c0 + row) * HW_ + s0 + c8;
  const float* xp = x   + eoff;
  float*       op = out + eoff;
  float (*T)[36] = xt[w];

#pragma unroll
  for (int p = 0; p < 4; ++p){
    const unsigned short* bp = bp0 + (size_t)(p * 32) * K_;
    short8 b0 = *(const short8*)(bp);
    short8 b1 = *(const short8*)(bp + 32);
    short8 b2 = *(const short8*)(bp + 16 * K_);
    short8 b3 = *(const short8*)(bp + 16 * K_ + 32);
    floatx4 acc0 = {0.f,0.f,0.f,0.f};
    floatx4 acc1 = {0.f,0.f,0.f,0.f};
    acc0 = __builtin_amdgcn_mfma_f32_16x16x32_bf16(a0, b0, acc0, 0, 0, 0);
    acc0 = __builtin_amdgcn_mfma_f32_16x16x32_bf16(a1, b1, acc0, 0, 0, 0);
    acc1 = __builtin_amdgcn_mfma_f32_16x16x32_bf16(a0, b2, acc1, 0, 0, 0);
    acc1 = __builtin_amdgcn_mfma_f32_16x16x32_bf16(a1, b3, acc1, 0, 0, 0);
    // acc layout: row = hi*4+r, col = lo (acc0: s+0..15, acc1: s+16..31)
#pragma unroll
    for (int r = 0; r < 4; ++r){
      T[hi * 4 + r][lo]      = acc0[r];
      T[hi * 4 + r][16 + lo] = acc1[r];
    }
    float4 v0 = *(const float4*)&T[row][c8];       // in-wave DS ordering
    float4 v1 = *(const float4*)&T[row][c8 + 4];
    float4 u0 = *(const float4*)(xp + p * 32);
    float4 u1 = *(const float4*)(xp + p * 32 + 4);
    float4 o0, o1;
    o0.x = u0.x + sc * v0.x; o0.y = u0.y + sc * v0.y;
    o0.z = u0.z + sc * v0.z; o0.w = u0.w + sc * v0.w;
    o1.x = u1.x + sc * v1.x; o1.y = u1.y + sc * v1.y;
    o1.z = u1.z + sc * v1.z; o1.w = u1.w + sc * v1.w;
    *(float4*)(op + p * 32)     = o0;
    *(float4*)(op + p * 32 + 4) = o1;
  }
}

extern "C" void kernel_launch(void* const* d_in, const int* in_sizes, int n_in,
                              void* d_out, int out_size, void* d_ws, size_t ws_size,
                              hipStream_t stream){
  const float* x     = (const float*)d_in[0];
  const float* y     = (const float*)d_in[1];
  const float* scale = (const float*)d_in[2];
  float* out = (float*)d_out;

  // ws layout (13 MiB total):
  //   partial : SPLITS * N*C*K f32  = 4 MiB    @ 0
  //   att     : N*C*K bf16          = 512 KiB  @ 4 MiB
  //   ybf     : N*K*HW bf16         = 4 MiB    @ 5 MiB
  //   ytr     : N*HW*K bf16         = 4 MiB    @ 9 MiB
  char* ws = (char*)d_ws;
  float*          partial = (float*)(ws);
  unsigned short* att     = (unsigned short*)(ws + (4u<<20));
  unsigned short* ybf     = (unsigned short*)(ws + (5u<<20));
  unsigned short* ytr     = (unsigned short*)(ws + (9u<<20));

  k_prep   <<<N_ * (HW_/64),       256, 0, stream>>>(y, ybf, ytr);
  k_energy <<<N_ * 32 * SPLITS,    256, 0, stream>>>(x, ybf, partial);
  k_softmax<<<(N_ * C_) / 4,       256, 0, stream>>>(partial, att);
  k_out    <<<N_ * 32 * 8,         256, 0, stream>>>(x, att, ytr, scale, out);
}